// Round 13
// baseline (202.875 us; speedup 1.0000x reference)
//
#include <hip/hip_runtime.h>
#include <math.h>

#define N_NODES 50000
#define M_FEAT 128
#define E_EDGES 800000
#define B_PAIRS 100000
#define PRP 8              // stride for p/q/Hs
#define PG 16              // stride for r/s

#define CH 2048                                  // edges per chunk
#define NCHUNK ((E_EDGES + CH - 1) / CH)         // 391
#define BS 64                                    // nodes per bucket
#define BSH 6                                    // log2(BS)
#define NBUCKET ((N_NODES + BS - 1) / BS)        // 782
#define HSZ (NBUCKET * NCHUNK)                   // 305,762
#define PROJ_BLOCKS 1100
#define SORT_CAP 1536      // LDS staging capacity (mean bucket = 1023, sigma ~32)

// offsets into the small fused-weight buffer Wsm (256 floats)
#define OFF_WPP 0
#define OFF_WQQ 49
#define OFF_WR  98
#define OFF_WS  161
#define OFF_BP  224
#define OFF_BQ  231
#define OFF_BR  238
#define OFF_BS  247

// ============ prep: coarse histogram + 4B edge packing + weight packing ============
// packed code: bucket(10) << 22 | dl(6) << 16 | src(16)

__global__ void __launch_bounds__(512) k_prep(
        const int4* __restrict__ edges2,          // 2 edges per int4
        const float* __restrict__ rp_w1, const float* __restrict__ g_w1,
        const float* __restrict__ w3, const float* __restrict__ b3,
        int* __restrict__ histT, uint2* __restrict__ packedE2,
        float* __restrict__ Wbig, float* __restrict__ Wsm, int* __restrict__ ticket) {
    int bid = blockIdx.x, tid = threadIdx.x;
    if (bid < NCHUNK) {
        __shared__ int cnt[NBUCKET];
        for (int i = tid; i < NBUCKET; i += 512) cnt[i] = 0;
        __syncthreads();
        int basePair = bid * (CH / 2);
#pragma unroll
        for (int k = 0; k < CH / 1024; ++k) {
            int pi = basePair + k * 512 + tid;
            if (pi < E_EDGES / 2) {
                int4 e2 = edges2[pi];
                int b0 = e2.y >> BSH, b1 = e2.w >> BSH;
                atomicAdd(&cnt[b0], 1);
                atomicAdd(&cnt[b1], 1);
                uint2 pc;
                pc.x = ((unsigned int)b0 << 22) | ((unsigned int)(e2.y & (BS - 1)) << 16)
                     | (unsigned int)e2.x;
                pc.y = ((unsigned int)b1 << 22) | ((unsigned int)(e2.w & (BS - 1)) << 16)
                     | (unsigned int)e2.z;
                packedE2[pi] = pc;
            }
        }
        __syncthreads();
        for (int i = tid; i < NBUCKET; i += 512) histT[i * NCHUNK + bid] = cnt[i];
        return;
    }
    if (bid < NCHUNK + 8) {   // Wbig: 4096 entries, 8 blocks x 512
        if (bid == NCHUNK && tid == 0) *ticket = 0;   // reset scan ticket each launch
        int t = (bid - NCHUNK) * 512 + tid;
        int m = t >> 5, o = t & 31;
        float v;
        if (o < 7)       v = rp_w1[m * 7 + o];
        else if (o < 14) v = rp_w1[(m + 128) * 7 + (o - 7)];
        else if (o < 23) v = g_w1[m * 9 + (o - 14)];
        else             v = g_w1[(m + 128) * 9 + (o - 23)];
        Wbig[m * 32 + o] = v;
        return;
    }
    // Wsm: 256 fused dot-products (threads 0..255)
    int t = tid;
    if (t >= 256) return;
    float acc = 0.f;
    if (t < 49) {
        int i = t / 7, j = t % 7;
        for (int m = 0; m < 128; ++m) acc = fmaf(w3[i * 128 + m], rp_w1[m * 7 + j], acc);
    } else if (t < 98) {
        int u = t - 49; int i = u / 7, j = u % 7;
        for (int m = 0; m < 128; ++m) acc = fmaf(w3[i * 128 + m], rp_w1[(m + 128) * 7 + j], acc);
    } else if (t < 161) {
        int u = t - 98; int i = u / 9, j = u % 9;
        for (int m = 0; m < 128; ++m) acc = fmaf(w3[i * 128 + m], g_w1[m * 9 + j], acc);
    } else if (t < 224) {
        int u = t - 161; int i = u / 9, j = u % 9;
        for (int m = 0; m < 128; ++m) acc = fmaf(w3[i * 128 + m], g_w1[(m + 128) * 9 + j], acc);
    } else if (t < 231) {
        int j = t - 224;
        for (int m = 0; m < 128; ++m) acc = fmaf(b3[m], rp_w1[m * 7 + j], acc);
    } else if (t < 238) {
        int j = t - 231;
        for (int m = 0; m < 128; ++m) acc = fmaf(b3[m], rp_w1[(m + 128) * 7 + j], acc);
    } else if (t < 247) {
        int j = t - 238;
        for (int m = 0; m < 128; ++m) acc = fmaf(b3[m], g_w1[m * 9 + j], acc);
    } else {
        int j = t - 247;
        for (int m = 0; m < 128; ++m) acc = fmaf(b3[m], g_w1[(m + 128) * 9 + j], acc);
    }
    Wsm[t] = acc;
}

// ============ per-bucket scan over chunks + fused base scan (last block) ============

__global__ void __launch_bounds__(512) k_scanB(
        const int* __restrict__ histT, int* __restrict__ histTs,
        int* __restrict__ btot, int* __restrict__ bucketBase, int* __restrict__ ticket) {
    __shared__ int sh[512];
    __shared__ int shb[1024];
    __shared__ int lastFlag;
    int b = blockIdx.x, tid = threadIdx.x;
    int v = (tid < NCHUNK) ? histT[b * NCHUNK + tid] : 0;
    sh[tid] = v;
    __syncthreads();
    for (int o = 1; o < 512; o <<= 1) {
        int t2 = (tid >= o) ? sh[tid - o] : 0;
        __syncthreads();
        sh[tid] += t2;
        __syncthreads();
    }
    if (tid < NCHUNK) histTs[b * NCHUNK + tid] = sh[tid] - v;   // local exclusive
    if (tid == 511) btot[b] = sh[511];                           // bucket total
    __threadfence();                                             // publish btot
    if (tid == 0) lastFlag = (atomicAdd(ticket, 1) == NBUCKET - 1);
    __syncthreads();
    if (!lastFlag) return;
    __threadfence();                                             // acquire others' btot
    // ---- last block: exclusive scan of 782 bucket totals ----
    int v0 = (tid < NBUCKET) ? btot[tid] : 0;
    int v1 = (tid + 512 < NBUCKET) ? btot[tid + 512] : 0;
    shb[tid] = v0;
    shb[tid + 512] = v1;
    __syncthreads();
    for (int o = 1; o < 1024; o <<= 1) {
        int t0 = (tid >= o) ? shb[tid - o] : 0;
        int t1 = (tid + 512 >= o) ? shb[tid + 512 - o] : 0;
        __syncthreads();
        shb[tid] += t0;
        shb[tid + 512] += t1;
        __syncthreads();
    }
    if (tid < NBUCKET) bucketBase[tid] = shb[tid] - v0;
    if (tid + 512 < NBUCKET) bucketBase[tid + 512] = shb[tid + 512] - v1;
    if (tid == 0) bucketBase[NBUCKET] = E_EDGES;
}

// ============ scatter (blocks 0..390, uint2 codes) || projection ============

__global__ void __launch_bounds__(512) k_scatProj(
        const uint2* __restrict__ packedE2, const int* __restrict__ histTs,
        const int* __restrict__ bucketBase, unsigned int* __restrict__ bucketed,
        const float* __restrict__ score, const float* __restrict__ Wbig,
        float* __restrict__ p, float* __restrict__ q,
        float* __restrict__ r, float* __restrict__ s) {
    __shared__ int offl[NBUCKET];
    const int bid = blockIdx.x, tid = threadIdx.x;
    if (bid < NCHUNK) {
        for (int i = tid; i < NBUCKET; i += 512)
            offl[i] = bucketBase[i] + histTs[i * NCHUNK + bid];
        __syncthreads();
        int basePair = bid * (CH / 2);
#pragma unroll
        for (int k = 0; k < CH / 1024; ++k) {
            int pi = basePair + k * 512 + tid;
            if (pi < E_EDGES / 2) {
                uint2 c2 = packedE2[pi];
                int pos0 = atomicAdd(&offl[c2.x >> 22], 1);
                bucketed[pos0] = c2.x & 0x3FFFFFu;
                int pos1 = atomicAdd(&offl[c2.y >> 22], 1);
                bucketed[pos1] = c2.y & 0x3FFFFFu;
            }
        }
        return;
    }
    // ---- projection: p,q,r,s = score @ Wbig ----
    int wave = (bid - NCHUNK) * 8 + (tid >> 6);
    int lane = tid & 63;
    const int nw = PROJ_BLOCKS * 8;
    int mg = lane >> 3, og = lane & 7;
    const float4* wb4 = reinterpret_cast<const float4*>(Wbig);
    float4 w[16];
#pragma unroll
    for (int i = 0; i < 16; ++i) w[i] = wb4[(mg * 16 + i) * 8 + og];
    for (int n = wave; n < N_NODES; n += nw) {
        const float4* srow = reinterpret_cast<const float4*>(score + n * M_FEAT + mg * 16);
        float a0 = 0.f, a1 = 0.f, a2 = 0.f, a3 = 0.f;
#pragma unroll
        for (int i = 0; i < 4; ++i) {
            float4 sv = srow[i];
            float se[4] = {sv.x, sv.y, sv.z, sv.w};
#pragma unroll
            for (int e = 0; e < 4; ++e) {
                float4 ww = w[i * 4 + e];
                a0 = fmaf(se[e], ww.x, a0);
                a1 = fmaf(se[e], ww.y, a1);
                a2 = fmaf(se[e], ww.z, a2);
                a3 = fmaf(se[e], ww.w, a3);
            }
        }
#pragma unroll
        for (int off = 32; off >= 8; off >>= 1) {
            a0 += __shfl_down(a0, off);
            a1 += __shfl_down(a1, off);
            a2 += __shfl_down(a2, off);
            a3 += __shfl_down(a3, off);
        }
        if (mg == 0) {
            float outv[4] = {a0, a1, a2, a3};
#pragma unroll
            for (int jj = 0; jj < 4; ++jj) {
                int o = og * 4 + jj;
                float v = outv[jj];
                if (o < 7)       p[n * PRP + o] = v;
                else if (o < 14) q[n * PRP + (o - 7)] = v;
                else if (o < 23) r[n * PG + (o - 14)] = v;
                else             s[n * PG + (o - 23)] = v;
            }
        }
    }
}

// ============ fused: per-bucket fine sort (LDS-staged) + round-0 edge pass ============

__global__ void __launch_bounds__(512) k_sortEdge0(
        const unsigned int* __restrict__ bucketed, const int* __restrict__ bucketBase,
        unsigned short* __restrict__ srcSorted16, int* __restrict__ off,
        const float* __restrict__ pIn, float* __restrict__ pOut,
        float* __restrict__ q, float* __restrict__ Hs,
        const float* __restrict__ w2, const float* __restrict__ b1,
        const float* __restrict__ b2, const float* __restrict__ Wsm) {
    __shared__ int cnt[BS], loc[BS], cur[BS], shs[BS];
    __shared__ unsigned short srcL[SORT_CAP];
    const int bid = blockIdx.x, tid = threadIdx.x;
    const int d0 = bid << BSH;

    if (tid < BS) { cnt[tid] = 0; cur[tid] = 0; }
    __syncthreads();
    const int base0 = bucketBase[bid];
    const int base1 = bucketBase[bid + 1];
    const int nb = base1 - base0;

    for (int i = base0 + tid; i < base1; i += 512)
        atomicAdd(&cnt[bucketed[i] >> 16], 1);
    __syncthreads();
    int v = (tid < BS) ? cnt[tid] : 0;
    if (tid < BS) shs[tid] = v;
    __syncthreads();
    for (int o = 1; o < BS; o <<= 1) {
        int t2 = (tid < BS && tid >= o) ? shs[tid - o] : 0;
        __syncthreads();
        if (tid < BS) shs[tid] += t2;
        __syncthreads();
    }
    if (tid < BS) {
        loc[tid] = shs[tid] - v;    // bucket-local exclusive prefix
        int n = d0 + tid;
        if (n < N_NODES) off[n] = base0 + loc[tid];
    }
    if (bid == 0 && tid == 0) off[N_NODES] = E_EDGES;
    __syncthreads();

    const bool inLds = (nb <= SORT_CAP);
    for (int i = base0 + tid; i < base1; i += 512) {
        unsigned int ec = bucketed[i];
        int dl = (int)(ec >> 16);
        int pos = loc[dl] + atomicAdd(&cur[dl], 1);
        unsigned short sv = (unsigned short)(ec & 0xFFFF);
        srcSorted16[base0 + pos] = sv;
        if (inLds) srcL[pos] = sv;
    }
    __syncthreads();

    // ---- round-0 edge MLP: 8 lanes per node, from LDS ----
    int li = tid >> 3, sub = tid & 7;
    int n = d0 + li;
    if (n >= N_NODES) return;
    float w2r[49], qr[7], b2r[7], acc[7];
#pragma unroll
    for (int i = 0; i < 49; ++i) w2r[i] = w2[i];
    {
        float4 qa = *reinterpret_cast<const float4*>(q + n * PRP);
        float4 qb4 = *reinterpret_cast<const float4*>(q + n * PRP + 4);
        qr[0] = qa.x + b1[0]; qr[1] = qa.y + b1[1]; qr[2] = qa.z + b1[2];
        qr[3] = qa.w + b1[3]; qr[4] = qb4.x + b1[4]; qr[5] = qb4.y + b1[5];
        qr[6] = qb4.z + b1[6];
    }
#pragma unroll
    for (int k = 0; k < 7; ++k) { b2r[k] = b2[k]; acc[k] = 0.f; }
    int l0 = loc[li], dg = cnt[li];
    for (int pos = l0 + sub; pos < l0 + dg; pos += 8) {
        int src = inLds ? (int)srcL[pos] : (int)srcSorted16[base0 + pos];
        float4 pa = *reinterpret_cast<const float4*>(pIn + src * PRP);
        float4 pb = *reinterpret_cast<const float4*>(pIn + src * PRP + 4);
        float h1[7];
        h1[0] = fmaxf(pa.x + qr[0], 0.f);
        h1[1] = fmaxf(pa.y + qr[1], 0.f);
        h1[2] = fmaxf(pa.z + qr[2], 0.f);
        h1[3] = fmaxf(pa.w + qr[3], 0.f);
        h1[4] = fmaxf(pb.x + qr[4], 0.f);
        h1[5] = fmaxf(pb.y + qr[5], 0.f);
        h1[6] = fmaxf(pb.z + qr[6], 0.f);
#pragma unroll
        for (int j = 0; j < 7; ++j) {
            float vv = b2r[j];
#pragma unroll
            for (int k = 0; k < 7; ++k) vv = fmaf(h1[k], w2r[k * 7 + j], vv);
            acc[j] += fmaxf(vv, 0.f);
        }
    }
#pragma unroll
    for (int j = 0; j < 7; ++j) {
        acc[j] += __shfl_down(acc[j], 4);
        acc[j] += __shfl_down(acc[j], 2);
        acc[j] += __shfl_down(acc[j], 1);
    }
    int baseLane = (threadIdx.x & 63) & ~7;
    float hb[7];
#pragma unroll
    for (int j = 0; j < 7; ++j) hb[j] = __shfl(acc[j], baseLane);
    if (sub < 7) {
        int j = sub;
        Hs[n * PRP + j] = hb[j];
        float degf = (float)dg;
        float vp = degf * Wsm[OFF_BP + j];
        float vq = degf * Wsm[OFF_BQ + j];
#pragma unroll
        for (int i2 = 0; i2 < 7; ++i2) {
            vp = fmaf(hb[i2], Wsm[OFF_WPP + i2 * 7 + j], vp);
            vq = fmaf(hb[i2], Wsm[OFF_WQQ + i2 * 7 + j], vq);
        }
        pOut[n * PRP + j] = pIn[n * PRP + j] + vp;
        q[n * PRP + j] += vq;
    }
}

// ============ edge rounds 1,2: CSR (uint16), 8 lanes/node, no atomics ============

template <int ROUND>
__global__ void __launch_bounds__(512) k_edgeC(
        const unsigned short* __restrict__ srcSorted16, const int* __restrict__ off,
        const float* __restrict__ pIn, float* __restrict__ pOut,
        float* __restrict__ q, float* __restrict__ Hs,
        const float* __restrict__ w2, const float* __restrict__ b1,
        const float* __restrict__ b2, const float* __restrict__ Wsm) {
    int gt = blockIdx.x * 512 + threadIdx.x;
    int n = gt >> 3, sub = gt & 7;
    if (n >= N_NODES) return;
    float w2r[49], qr[7], b2r[7], acc[7];
#pragma unroll
    for (int i = 0; i < 49; ++i) w2r[i] = w2[i];
    {
        float4 qa = *reinterpret_cast<const float4*>(q + n * PRP);
        float4 qb4 = *reinterpret_cast<const float4*>(q + n * PRP + 4);
        qr[0] = qa.x + b1[0]; qr[1] = qa.y + b1[1]; qr[2] = qa.z + b1[2];
        qr[3] = qa.w + b1[3]; qr[4] = qb4.x + b1[4]; qr[5] = qb4.y + b1[5];
        qr[6] = qb4.z + b1[6];
    }
#pragma unroll
    for (int k = 0; k < 7; ++k) { b2r[k] = b2[k]; acc[k] = 0.f; }
    int s0 = off[n], s1 = off[n + 1];
    for (int pos = s0 + sub; pos < s1; pos += 8) {
        int src = (int)srcSorted16[pos];
        float4 pa = *reinterpret_cast<const float4*>(pIn + src * PRP);
        float4 pb = *reinterpret_cast<const float4*>(pIn + src * PRP + 4);
        float h1[7];
        h1[0] = fmaxf(pa.x + qr[0], 0.f);
        h1[1] = fmaxf(pa.y + qr[1], 0.f);
        h1[2] = fmaxf(pa.z + qr[2], 0.f);
        h1[3] = fmaxf(pa.w + qr[3], 0.f);
        h1[4] = fmaxf(pb.x + qr[4], 0.f);
        h1[5] = fmaxf(pb.y + qr[5], 0.f);
        h1[6] = fmaxf(pb.z + qr[6], 0.f);
#pragma unroll
        for (int j = 0; j < 7; ++j) {
            float vv = b2r[j];
#pragma unroll
            for (int k = 0; k < 7; ++k) vv = fmaf(h1[k], w2r[k * 7 + j], vv);
            acc[j] += fmaxf(vv, 0.f);
        }
    }
#pragma unroll
    for (int j = 0; j < 7; ++j) {
        acc[j] += __shfl_down(acc[j], 4);
        acc[j] += __shfl_down(acc[j], 2);
        acc[j] += __shfl_down(acc[j], 1);
    }
    int baseLane = (threadIdx.x & 63) & ~7;
    float hb[7];
#pragma unroll
    for (int j = 0; j < 7; ++j) hb[j] = __shfl(acc[j], baseLane);
    if (sub < 7) {
        int j = sub;
        Hs[n * PRP + j] += hb[j];
        if (ROUND < 2) {
            float degf = (float)(s1 - s0);
            float vp = degf * Wsm[OFF_BP + j];
            float vq = degf * Wsm[OFF_BQ + j];
#pragma unroll
            for (int i2 = 0; i2 < 7; ++i2) {
                vp = fmaf(hb[i2], Wsm[OFF_WPP + i2 * 7 + j], vp);
                vq = fmaf(hb[i2], Wsm[OFF_WQQ + i2 * 7 + j], vq);
            }
            pOut[n * PRP + j] = pIn[n * PRP + j] + vp;
            q[n * PRP + j] += vq;
        }
    }
}

// ============ pair scorer with fused r/s finalization (deg from CSR) ============

__global__ void k_pair(const int2* __restrict__ lab2, const float* __restrict__ r,
                       const float* __restrict__ s, const float* __restrict__ Hs,
                       const int* __restrict__ off, const float* __restrict__ Wsm,
                       const float* __restrict__ w2, const float* __restrict__ b1,
                       const float* __restrict__ b2, const float* __restrict__ w3,
                       const float* __restrict__ b3, float* __restrict__ out) {
    int b = blockIdx.x * blockDim.x + threadIdx.x;
    if (b >= B_PAIRS) return;
    int2 ab = lab2[b];
    int a0 = ab.x, a1 = ab.y;
    float h0[7], h1v[7];
#pragma unroll
    for (int k = 0; k < 7; ++k) { h0[k] = Hs[a0 * PRP + k]; h1v[k] = Hs[a1 * PRP + k]; }
    float d30 = 3.f * (float)(off[a0 + 1] - off[a0]);
    float d31 = 3.f * (float)(off[a1 + 1] - off[a1]);
    float g1[9];
#pragma unroll
    for (int j = 0; j < 9; ++j) {
        float vr = r[a0 * PG + j] + d30 * Wsm[OFF_BR + j];
        float vs = s[a1 * PG + j] + d31 * Wsm[OFF_BS + j];
#pragma unroll
        for (int i = 0; i < 7; ++i) {
            vr = fmaf(h0[i], Wsm[OFF_WR + i * 9 + j], vr);
            vs = fmaf(h1v[i], Wsm[OFF_WS + i * 9 + j], vs);
        }
        g1[j] = fmaxf(vr + vs + b1[j], 0.f);
    }
    float logit = b3[0];
#pragma unroll
    for (int j = 0; j < 9; ++j) {
        float v = b2[j];
#pragma unroll
        for (int k = 0; k < 9; ++k) v = fmaf(g1[k], w2[k * 9 + j], v);
        logit = fmaf(fmaxf(v, 0.f), w3[j], logit);
    }
    out[b] = 1.f / (1.f + expf(-logit));
}

// ---------------- launch: 7 dispatches ----------------

extern "C" void kernel_launch(void* const* d_in, const int* in_sizes, int n_in,
                              void* d_out, int out_size, void* d_ws, size_t ws_size,
                              hipStream_t stream) {
    const float* score = (const float*)d_in[0];
    const int4*  edges2 = (const int4*)d_in[1];
    const int2*  lab2  = (const int2*)d_in[2];
    const float* rp_w1 = (const float*)d_in[3];
    const float* rp_b1 = (const float*)d_in[4];
    const float* rp_w2 = (const float*)d_in[5];
    const float* rp_b2 = (const float*)d_in[6];
    const float* rp_w3 = (const float*)d_in[7];
    const float* rp_b3 = (const float*)d_in[8];
    const float* g_w1  = (const float*)d_in[9];
    const float* g_b1  = (const float*)d_in[10];
    const float* g_w2  = (const float*)d_in[11];
    const float* g_b2  = (const float*)d_in[12];
    const float* g_w3  = (const float*)d_in[13];
    const float* g_b3  = (const float*)d_in[14];
    float* out = (float*)d_out;

    float* ws   = (float*)d_ws;
    float* pA   = ws;                      // N*8
    float* pB   = pA + N_NODES * PRP;      // N*8
    float* q    = pB + N_NODES * PRP;      // N*8
    float* Hs   = q + N_NODES * PRP;       // N*8
    float* r    = Hs + N_NODES * PRP;      // N*16
    float* s    = r + N_NODES * PG;        // N*16
    float* Wbig = s + N_NODES * PG;        // 4096
    float* Wsm  = Wbig + 4096;             // 256
    unsigned int* packedE  = (unsigned int*)(Wsm + 256);   // E (uint2-aligned)
    unsigned int* bucketed = packedE + E_EDGES;            // E
    unsigned short* srcSorted16 = (unsigned short*)(bucketed + E_EDGES);  // E uint16
    int* histT      = (int*)(srcSorted16 + E_EDGES);       // HSZ
    int* histTs     = histT + HSZ;                         // HSZ
    int* btot       = histTs + HSZ;                        // NBUCKET
    int* bucketBase = btot + NBUCKET;                      // NBUCKET+1
    int* off        = bucketBase + NBUCKET + 1;            // N+1
    int* ticket     = off + N_NODES + 1;                   // 1

    k_prep<<<NCHUNK + 9, 512, 0, stream>>>(edges2, rp_w1, g_w1, rp_w3, rp_b3,
                                           histT, (uint2*)packedE, Wbig, Wsm, ticket);
    k_scanB<<<NBUCKET, 512, 0, stream>>>(histT, histTs, btot, bucketBase, ticket);
    k_scatProj<<<NCHUNK + PROJ_BLOCKS, 512, 0, stream>>>((const uint2*)packedE, histTs,
                                                         bucketBase, bucketed, score, Wbig,
                                                         pA, q, r, s);
    k_sortEdge0<<<NBUCKET, 512, 0, stream>>>(bucketed, bucketBase, srcSorted16, off,
                                             pA, pB, q, Hs, rp_w2, rp_b1, rp_b2, Wsm);
    k_edgeC<1><<<(8 * N_NODES + 511) / 512, 512, 0, stream>>>(srcSorted16, off, pB, pA, q, Hs,
                                                              rp_w2, rp_b1, rp_b2, Wsm);
    k_edgeC<2><<<(8 * N_NODES + 511) / 512, 512, 0, stream>>>(srcSorted16, off, pA, pB, q, Hs,
                                                              rp_w2, rp_b1, rp_b2, Wsm);
    k_pair<<<(B_PAIRS + 255) / 256, 256, 0, stream>>>(lab2, r, s, Hs, off, Wsm,
                                                      g_w2, g_b1, g_b2, g_w3, g_b3, out);
}

// Round 14
// 104.851 us; speedup vs baseline: 1.9349x; 1.9349x over previous
//
#include <hip/hip_runtime.h>
#include <math.h>

#define N_NODES 50000
#define M_FEAT 128
#define E_EDGES 800000
#define B_PAIRS 100000
#define PRP 8              // stride for p/q/Hs
#define PG 16              // stride for r/s

#define CH 2048                                  // edges per chunk
#define NCHUNK ((E_EDGES + CH - 1) / CH)         // 391
#define BS 64                                    // nodes per bucket
#define BSH 6                                    // log2(BS)
#define NBUCKET ((N_NODES + BS - 1) / BS)        // 782
#define HSZ (NBUCKET * NCHUNK)                   // 305,762
#define PROJ_BLOCKS 1100
#define SORT_CAP 1536      // LDS staging capacity (mean bucket = 1023, sigma ~32)

// offsets into the small fused-weight buffer Wsm (256 floats)
#define OFF_WPP 0
#define OFF_WQQ 49
#define OFF_WR  98
#define OFF_WS  161
#define OFF_BP  224
#define OFF_BQ  231
#define OFF_BR  238
#define OFF_BS  247

// ============ prep: coarse histogram + 4B edge packing + weight packing ============
// packed code: bucket(10) << 22 | dl(6) << 16 | src(16)

__global__ void __launch_bounds__(512) k_prep(
        const int4* __restrict__ edges2,          // 2 edges per int4
        const float* __restrict__ rp_w1, const float* __restrict__ g_w1,
        const float* __restrict__ w3, const float* __restrict__ b3,
        int* __restrict__ histT, uint2* __restrict__ packedE2,
        float* __restrict__ Wbig, float* __restrict__ Wsm) {
    int bid = blockIdx.x, tid = threadIdx.x;
    if (bid < NCHUNK) {
        __shared__ int cnt[NBUCKET];
        for (int i = tid; i < NBUCKET; i += 512) cnt[i] = 0;
        __syncthreads();
        int basePair = bid * (CH / 2);
#pragma unroll
        for (int k = 0; k < CH / 1024; ++k) {
            int pi = basePair + k * 512 + tid;
            if (pi < E_EDGES / 2) {
                int4 e2 = edges2[pi];
                int b0 = e2.y >> BSH, b1 = e2.w >> BSH;
                atomicAdd(&cnt[b0], 1);
                atomicAdd(&cnt[b1], 1);
                uint2 pc;
                pc.x = ((unsigned int)b0 << 22) | ((unsigned int)(e2.y & (BS - 1)) << 16)
                     | (unsigned int)e2.x;
                pc.y = ((unsigned int)b1 << 22) | ((unsigned int)(e2.w & (BS - 1)) << 16)
                     | (unsigned int)e2.z;
                packedE2[pi] = pc;
            }
        }
        __syncthreads();
        for (int i = tid; i < NBUCKET; i += 512) histT[i * NCHUNK + bid] = cnt[i];
        return;
    }
    if (bid < NCHUNK + 8) {   // Wbig: 4096 entries, 8 blocks x 512
        int t = (bid - NCHUNK) * 512 + tid;
        int m = t >> 5, o = t & 31;
        float v;
        if (o < 7)       v = rp_w1[m * 7 + o];
        else if (o < 14) v = rp_w1[(m + 128) * 7 + (o - 7)];
        else if (o < 23) v = g_w1[m * 9 + (o - 14)];
        else             v = g_w1[(m + 128) * 9 + (o - 23)];
        Wbig[m * 32 + o] = v;
        return;
    }
    // Wsm: 256 fused dot-products (threads 0..255)
    int t = tid;
    if (t >= 256) return;
    float acc = 0.f;
    if (t < 49) {
        int i = t / 7, j = t % 7;
        for (int m = 0; m < 128; ++m) acc = fmaf(w3[i * 128 + m], rp_w1[m * 7 + j], acc);
    } else if (t < 98) {
        int u = t - 49; int i = u / 7, j = u % 7;
        for (int m = 0; m < 128; ++m) acc = fmaf(w3[i * 128 + m], rp_w1[(m + 128) * 7 + j], acc);
    } else if (t < 161) {
        int u = t - 98; int i = u / 9, j = u % 9;
        for (int m = 0; m < 128; ++m) acc = fmaf(w3[i * 128 + m], g_w1[m * 9 + j], acc);
    } else if (t < 224) {
        int u = t - 161; int i = u / 9, j = u % 9;
        for (int m = 0; m < 128; ++m) acc = fmaf(w3[i * 128 + m], g_w1[(m + 128) * 9 + j], acc);
    } else if (t < 231) {
        int j = t - 224;
        for (int m = 0; m < 128; ++m) acc = fmaf(b3[m], rp_w1[m * 7 + j], acc);
    } else if (t < 238) {
        int j = t - 231;
        for (int m = 0; m < 128; ++m) acc = fmaf(b3[m], rp_w1[(m + 128) * 7 + j], acc);
    } else if (t < 247) {
        int j = t - 238;
        for (int m = 0; m < 128; ++m) acc = fmaf(b3[m], g_w1[m * 9 + j], acc);
    } else {
        int j = t - 247;
        for (int m = 0; m < 128; ++m) acc = fmaf(b3[m], g_w1[(m + 128) * 9 + j], acc);
    }
    Wsm[t] = acc;
}

// ============ per-bucket exclusive scan over chunks (782 WGs x 512) ============

__global__ void __launch_bounds__(512) k_scanB(const int* __restrict__ histT,
                                               int* __restrict__ histTs,
                                               int* __restrict__ btot) {
    __shared__ int sh[512];
    int b = blockIdx.x, tid = threadIdx.x;
    int v = (tid < NCHUNK) ? histT[b * NCHUNK + tid] : 0;
    sh[tid] = v;
    __syncthreads();
    for (int o = 1; o < 512; o <<= 1) {
        int t2 = (tid >= o) ? sh[tid - o] : 0;
        __syncthreads();
        sh[tid] += t2;
        __syncthreads();
    }
    if (tid < NCHUNK) histTs[b * NCHUNK + tid] = sh[tid] - v;   // local exclusive
    if (tid == 511) btot[b] = sh[511];                           // bucket total
}

// ============ exclusive scan of bucket totals (1 WG x 1024) ============

__global__ void k_scanBase(const int* __restrict__ btot, int* __restrict__ bucketBase) {
    __shared__ int sh[1024];
    int tid = threadIdx.x;
    int v = (tid < NBUCKET) ? btot[tid] : 0;
    sh[tid] = v;
    __syncthreads();
    for (int o = 1; o < 1024; o <<= 1) {
        int t2 = (tid >= o) ? sh[tid - o] : 0;
        __syncthreads();
        sh[tid] += t2;
        __syncthreads();
    }
    if (tid < NBUCKET) bucketBase[tid] = sh[tid] - v;
    if (tid == 0) bucketBase[NBUCKET] = E_EDGES;
}

// ============ scatter (blocks 0..390, uint2 codes) || projection ============

__global__ void __launch_bounds__(512) k_scatProj(
        const uint2* __restrict__ packedE2, const int* __restrict__ histTs,
        const int* __restrict__ bucketBase, unsigned int* __restrict__ bucketed,
        const float* __restrict__ score, const float* __restrict__ Wbig,
        float* __restrict__ p, float* __restrict__ q,
        float* __restrict__ r, float* __restrict__ s) {
    __shared__ int offl[NBUCKET];
    const int bid = blockIdx.x, tid = threadIdx.x;
    if (bid < NCHUNK) {
        for (int i = tid; i < NBUCKET; i += 512)
            offl[i] = bucketBase[i] + histTs[i * NCHUNK + bid];
        __syncthreads();
        int basePair = bid * (CH / 2);
#pragma unroll
        for (int k = 0; k < CH / 1024; ++k) {
            int pi = basePair + k * 512 + tid;
            if (pi < E_EDGES / 2) {
                uint2 c2 = packedE2[pi];
                int pos0 = atomicAdd(&offl[c2.x >> 22], 1);
                bucketed[pos0] = c2.x & 0x3FFFFFu;
                int pos1 = atomicAdd(&offl[c2.y >> 22], 1);
                bucketed[pos1] = c2.y & 0x3FFFFFu;
            }
        }
        return;
    }
    // ---- projection: p,q,r,s = score @ Wbig ----
    int wave = (bid - NCHUNK) * 8 + (tid >> 6);
    int lane = tid & 63;
    const int nw = PROJ_BLOCKS * 8;
    int mg = lane >> 3, og = lane & 7;
    const float4* wb4 = reinterpret_cast<const float4*>(Wbig);
    float4 w[16];
#pragma unroll
    for (int i = 0; i < 16; ++i) w[i] = wb4[(mg * 16 + i) * 8 + og];
    for (int n = wave; n < N_NODES; n += nw) {
        const float4* srow = reinterpret_cast<const float4*>(score + n * M_FEAT + mg * 16);
        float a0 = 0.f, a1 = 0.f, a2 = 0.f, a3 = 0.f;
#pragma unroll
        for (int i = 0; i < 4; ++i) {
            float4 sv = srow[i];
            float se[4] = {sv.x, sv.y, sv.z, sv.w};
#pragma unroll
            for (int e = 0; e < 4; ++e) {
                float4 ww = w[i * 4 + e];
                a0 = fmaf(se[e], ww.x, a0);
                a1 = fmaf(se[e], ww.y, a1);
                a2 = fmaf(se[e], ww.z, a2);
                a3 = fmaf(se[e], ww.w, a3);
            }
        }
#pragma unroll
        for (int off = 32; off >= 8; off >>= 1) {
            a0 += __shfl_down(a0, off);
            a1 += __shfl_down(a1, off);
            a2 += __shfl_down(a2, off);
            a3 += __shfl_down(a3, off);
        }
        if (mg == 0) {
            float outv[4] = {a0, a1, a2, a3};
#pragma unroll
            for (int jj = 0; jj < 4; ++jj) {
                int o = og * 4 + jj;
                float v = outv[jj];
                if (o < 7)       p[n * PRP + o] = v;
                else if (o < 14) q[n * PRP + (o - 7)] = v;
                else if (o < 23) r[n * PG + (o - 14)] = v;
                else             s[n * PG + (o - 23)] = v;
            }
        }
    }
}

// ============ fused: per-bucket fine sort (LDS-staged) + round-0 edge pass ============

__global__ void __launch_bounds__(512) k_sortEdge0(
        const unsigned int* __restrict__ bucketed, const int* __restrict__ bucketBase,
        unsigned short* __restrict__ srcSorted16, int* __restrict__ off,
        const float* __restrict__ pIn, float* __restrict__ pOut,
        float* __restrict__ q, float* __restrict__ Hs,
        const float* __restrict__ w2, const float* __restrict__ b1,
        const float* __restrict__ b2, const float* __restrict__ Wsm) {
    __shared__ int cnt[BS], loc[BS], cur[BS], shs[BS];
    __shared__ unsigned short srcL[SORT_CAP];
    const int bid = blockIdx.x, tid = threadIdx.x;
    const int d0 = bid << BSH;

    if (tid < BS) { cnt[tid] = 0; cur[tid] = 0; }
    __syncthreads();
    const int base0 = bucketBase[bid];
    const int base1 = bucketBase[bid + 1];
    const int nb = base1 - base0;

    for (int i = base0 + tid; i < base1; i += 512)
        atomicAdd(&cnt[bucketed[i] >> 16], 1);
    __syncthreads();
    int v = (tid < BS) ? cnt[tid] : 0;
    if (tid < BS) shs[tid] = v;
    __syncthreads();
    for (int o = 1; o < BS; o <<= 1) {
        int t2 = (tid < BS && tid >= o) ? shs[tid - o] : 0;
        __syncthreads();
        if (tid < BS) shs[tid] += t2;
        __syncthreads();
    }
    if (tid < BS) {
        loc[tid] = shs[tid] - v;    // bucket-local exclusive prefix
        int n = d0 + tid;
        if (n < N_NODES) off[n] = base0 + loc[tid];
    }
    if (bid == 0 && tid == 0) off[N_NODES] = E_EDGES;
    __syncthreads();

    const bool inLds = (nb <= SORT_CAP);
    for (int i = base0 + tid; i < base1; i += 512) {
        unsigned int ec = bucketed[i];
        int dl = (int)(ec >> 16);
        int pos = loc[dl] + atomicAdd(&cur[dl], 1);
        unsigned short sv = (unsigned short)(ec & 0xFFFF);
        srcSorted16[base0 + pos] = sv;
        if (inLds) srcL[pos] = sv;
    }
    __syncthreads();

    // ---- round-0 edge MLP: 8 lanes per node, from LDS ----
    int li = tid >> 3, sub = tid & 7;
    int n = d0 + li;
    if (n >= N_NODES) return;
    float w2r[49], qr[7], b2r[7], acc[7];
#pragma unroll
    for (int i = 0; i < 49; ++i) w2r[i] = w2[i];
    {
        float4 qa = *reinterpret_cast<const float4*>(q + n * PRP);
        float4 qb4 = *reinterpret_cast<const float4*>(q + n * PRP + 4);
        qr[0] = qa.x + b1[0]; qr[1] = qa.y + b1[1]; qr[2] = qa.z + b1[2];
        qr[3] = qa.w + b1[3]; qr[4] = qb4.x + b1[4]; qr[5] = qb4.y + b1[5];
        qr[6] = qb4.z + b1[6];
    }
#pragma unroll
    for (int k = 0; k < 7; ++k) { b2r[k] = b2[k]; acc[k] = 0.f; }
    int l0 = loc[li], dg = cnt[li];
    for (int pos = l0 + sub; pos < l0 + dg; pos += 8) {
        int src = inLds ? (int)srcL[pos] : (int)srcSorted16[base0 + pos];
        float4 pa = *reinterpret_cast<const float4*>(pIn + src * PRP);
        float4 pb = *reinterpret_cast<const float4*>(pIn + src * PRP + 4);
        float h1[7];
        h1[0] = fmaxf(pa.x + qr[0], 0.f);
        h1[1] = fmaxf(pa.y + qr[1], 0.f);
        h1[2] = fmaxf(pa.z + qr[2], 0.f);
        h1[3] = fmaxf(pa.w + qr[3], 0.f);
        h1[4] = fmaxf(pb.x + qr[4], 0.f);
        h1[5] = fmaxf(pb.y + qr[5], 0.f);
        h1[6] = fmaxf(pb.z + qr[6], 0.f);
#pragma unroll
        for (int j = 0; j < 7; ++j) {
            float vv = b2r[j];
#pragma unroll
            for (int k = 0; k < 7; ++k) vv = fmaf(h1[k], w2r[k * 7 + j], vv);
            acc[j] += fmaxf(vv, 0.f);
        }
    }
#pragma unroll
    for (int j = 0; j < 7; ++j) {
        acc[j] += __shfl_down(acc[j], 4);
        acc[j] += __shfl_down(acc[j], 2);
        acc[j] += __shfl_down(acc[j], 1);
    }
    int baseLane = (threadIdx.x & 63) & ~7;
    float hb[7];
#pragma unroll
    for (int j = 0; j < 7; ++j) hb[j] = __shfl(acc[j], baseLane);
    if (sub < 7) {
        int j = sub;
        Hs[n * PRP + j] = hb[j];
        float degf = (float)dg;
        float vp = degf * Wsm[OFF_BP + j];
        float vq = degf * Wsm[OFF_BQ + j];
#pragma unroll
        for (int i2 = 0; i2 < 7; ++i2) {
            vp = fmaf(hb[i2], Wsm[OFF_WPP + i2 * 7 + j], vp);
            vq = fmaf(hb[i2], Wsm[OFF_WQQ + i2 * 7 + j], vq);
        }
        pOut[n * PRP + j] = pIn[n * PRP + j] + vp;
        q[n * PRP + j] += vq;
    }
}

// ============ edge rounds 1,2: CSR (uint16), 8 lanes/node, no atomics ============

template <int ROUND>
__global__ void __launch_bounds__(512) k_edgeC(
        const unsigned short* __restrict__ srcSorted16, const int* __restrict__ off,
        const float* __restrict__ pIn, float* __restrict__ pOut,
        float* __restrict__ q, float* __restrict__ Hs,
        const float* __restrict__ w2, const float* __restrict__ b1,
        const float* __restrict__ b2, const float* __restrict__ Wsm) {
    int gt = blockIdx.x * 512 + threadIdx.x;
    int n = gt >> 3, sub = gt & 7;
    if (n >= N_NODES) return;
    float w2r[49], qr[7], b2r[7], acc[7];
#pragma unroll
    for (int i = 0; i < 49; ++i) w2r[i] = w2[i];
    {
        float4 qa = *reinterpret_cast<const float4*>(q + n * PRP);
        float4 qb4 = *reinterpret_cast<const float4*>(q + n * PRP + 4);
        qr[0] = qa.x + b1[0]; qr[1] = qa.y + b1[1]; qr[2] = qa.z + b1[2];
        qr[3] = qa.w + b1[3]; qr[4] = qb4.x + b1[4]; qr[5] = qb4.y + b1[5];
        qr[6] = qb4.z + b1[6];
    }
#pragma unroll
    for (int k = 0; k < 7; ++k) { b2r[k] = b2[k]; acc[k] = 0.f; }
    int s0 = off[n], s1 = off[n + 1];
    for (int pos = s0 + sub; pos < s1; pos += 8) {
        int src = (int)srcSorted16[pos];
        float4 pa = *reinterpret_cast<const float4*>(pIn + src * PRP);
        float4 pb = *reinterpret_cast<const float4*>(pIn + src * PRP + 4);
        float h1[7];
        h1[0] = fmaxf(pa.x + qr[0], 0.f);
        h1[1] = fmaxf(pa.y + qr[1], 0.f);
        h1[2] = fmaxf(pa.z + qr[2], 0.f);
        h1[3] = fmaxf(pa.w + qr[3], 0.f);
        h1[4] = fmaxf(pb.x + qr[4], 0.f);
        h1[5] = fmaxf(pb.y + qr[5], 0.f);
        h1[6] = fmaxf(pb.z + qr[6], 0.f);
#pragma unroll
        for (int j = 0; j < 7; ++j) {
            float vv = b2r[j];
#pragma unroll
            for (int k = 0; k < 7; ++k) vv = fmaf(h1[k], w2r[k * 7 + j], vv);
            acc[j] += fmaxf(vv, 0.f);
        }
    }
#pragma unroll
    for (int j = 0; j < 7; ++j) {
        acc[j] += __shfl_down(acc[j], 4);
        acc[j] += __shfl_down(acc[j], 2);
        acc[j] += __shfl_down(acc[j], 1);
    }
    int baseLane = (threadIdx.x & 63) & ~7;
    float hb[7];
#pragma unroll
    for (int j = 0; j < 7; ++j) hb[j] = __shfl(acc[j], baseLane);
    if (sub < 7) {
        int j = sub;
        Hs[n * PRP + j] += hb[j];
        if (ROUND < 2) {
            float degf = (float)(s1 - s0);
            float vp = degf * Wsm[OFF_BP + j];
            float vq = degf * Wsm[OFF_BQ + j];
#pragma unroll
            for (int i2 = 0; i2 < 7; ++i2) {
                vp = fmaf(hb[i2], Wsm[OFF_WPP + i2 * 7 + j], vp);
                vq = fmaf(hb[i2], Wsm[OFF_WQQ + i2 * 7 + j], vq);
            }
            pOut[n * PRP + j] = pIn[n * PRP + j] + vp;
            q[n * PRP + j] += vq;
        }
    }
}

// ============ pair scorer with fused r/s finalization (deg from CSR) ============

__global__ void k_pair(const int2* __restrict__ lab2, const float* __restrict__ r,
                       const float* __restrict__ s, const float* __restrict__ Hs,
                       const int* __restrict__ off, const float* __restrict__ Wsm,
                       const float* __restrict__ w2, const float* __restrict__ b1,
                       const float* __restrict__ b2, const float* __restrict__ w3,
                       const float* __restrict__ b3, float* __restrict__ out) {
    int b = blockIdx.x * blockDim.x + threadIdx.x;
    if (b >= B_PAIRS) return;
    int2 ab = lab2[b];
    int a0 = ab.x, a1 = ab.y;
    float h0[7], h1v[7];
#pragma unroll
    for (int k = 0; k < 7; ++k) { h0[k] = Hs[a0 * PRP + k]; h1v[k] = Hs[a1 * PRP + k]; }
    float d30 = 3.f * (float)(off[a0 + 1] - off[a0]);
    float d31 = 3.f * (float)(off[a1 + 1] - off[a1]);
    float g1[9];
#pragma unroll
    for (int j = 0; j < 9; ++j) {
        float vr = r[a0 * PG + j] + d30 * Wsm[OFF_BR + j];
        float vs = s[a1 * PG + j] + d31 * Wsm[OFF_BS + j];
#pragma unroll
        for (int i = 0; i < 7; ++i) {
            vr = fmaf(h0[i], Wsm[OFF_WR + i * 9 + j], vr);
            vs = fmaf(h1v[i], Wsm[OFF_WS + i * 9 + j], vs);
        }
        g1[j] = fmaxf(vr + vs + b1[j], 0.f);
    }
    float logit = b3[0];
#pragma unroll
    for (int j = 0; j < 9; ++j) {
        float v = b2[j];
#pragma unroll
        for (int k = 0; k < 9; ++k) v = fmaf(g1[k], w2[k * 9 + j], v);
        logit = fmaf(fmaxf(v, 0.f), w3[j], logit);
    }
    out[b] = 1.f / (1.f + expf(-logit));
}

// ---------------- launch: 8 dispatches ----------------

extern "C" void kernel_launch(void* const* d_in, const int* in_sizes, int n_in,
                              void* d_out, int out_size, void* d_ws, size_t ws_size,
                              hipStream_t stream) {
    const float* score = (const float*)d_in[0];
    const int4*  edges2 = (const int4*)d_in[1];
    const int2*  lab2  = (const int2*)d_in[2];
    const float* rp_w1 = (const float*)d_in[3];
    const float* rp_b1 = (const float*)d_in[4];
    const float* rp_w2 = (const float*)d_in[5];
    const float* rp_b2 = (const float*)d_in[6];
    const float* rp_w3 = (const float*)d_in[7];
    const float* rp_b3 = (const float*)d_in[8];
    const float* g_w1  = (const float*)d_in[9];
    const float* g_b1  = (const float*)d_in[10];
    const float* g_w2  = (const float*)d_in[11];
    const float* g_b2  = (const float*)d_in[12];
    const float* g_w3  = (const float*)d_in[13];
    const float* g_b3  = (const float*)d_in[14];
    float* out = (float*)d_out;

    float* ws   = (float*)d_ws;
    float* pA   = ws;                      // N*8
    float* pB   = pA + N_NODES * PRP;      // N*8
    float* q    = pB + N_NODES * PRP;      // N*8
    float* Hs   = q + N_NODES * PRP;       // N*8
    float* r    = Hs + N_NODES * PRP;      // N*16
    float* s    = r + N_NODES * PG;        // N*16
    float* Wbig = s + N_NODES * PG;        // 4096
    float* Wsm  = Wbig + 4096;             // 256
    unsigned int* packedE  = (unsigned int*)(Wsm + 256);   // E (uint2-aligned)
    unsigned int* bucketed = packedE + E_EDGES;            // E
    unsigned short* srcSorted16 = (unsigned short*)(bucketed + E_EDGES);  // E uint16
    int* histT      = (int*)(srcSorted16 + E_EDGES);       // HSZ
    int* histTs     = histT + HSZ;                         // HSZ
    int* btot       = histTs + HSZ;                        // NBUCKET
    int* bucketBase = btot + NBUCKET;                      // NBUCKET+1
    int* off        = bucketBase + NBUCKET + 1;            // N+1

    k_prep<<<NCHUNK + 9, 512, 0, stream>>>(edges2, rp_w1, g_w1, rp_w3, rp_b3,
                                           histT, (uint2*)packedE, Wbig, Wsm);
    k_scanB<<<NBUCKET, 512, 0, stream>>>(histT, histTs, btot);
    k_scanBase<<<1, 1024, 0, stream>>>(btot, bucketBase);
    k_scatProj<<<NCHUNK + PROJ_BLOCKS, 512, 0, stream>>>((const uint2*)packedE, histTs,
                                                         bucketBase, bucketed, score, Wbig,
                                                         pA, q, r, s);
    k_sortEdge0<<<NBUCKET, 512, 0, stream>>>(bucketed, bucketBase, srcSorted16, off,
                                             pA, pB, q, Hs, rp_w2, rp_b1, rp_b2, Wsm);
    k_edgeC<1><<<(8 * N_NODES + 511) / 512, 512, 0, stream>>>(srcSorted16, off, pB, pA, q, Hs,
                                                              rp_w2, rp_b1, rp_b2, Wsm);
    k_edgeC<2><<<(8 * N_NODES + 511) / 512, 512, 0, stream>>>(srcSorted16, off, pA, pB, q, Hs,
                                                              rp_w2, rp_b1, rp_b2, Wsm);
    k_pair<<<(B_PAIRS + 255) / 256, 256, 0, stream>>>(lab2, r, s, Hs, off, Wsm,
                                                      g_w2, g_b1, g_b2, g_w3, g_b3, out);
}

// Round 15
// 98.241 us; speedup vs baseline: 2.0651x; 1.0673x over previous
//
#include <hip/hip_runtime.h>
#include <math.h>

#define N_NODES 50000
#define M_FEAT 128
#define E_EDGES 800000
#define B_PAIRS 100000
#define PRP 8              // stride for p/q/Hs
#define PG 16              // stride for r/s

#define CH 2048                                  // edges per chunk (hist granularity)
#define NCHUNK ((E_EDGES + CH - 1) / CH)         // 391
#define GRP 4                                    // chunks per scatter block
#define NSCAT ((NCHUNK + GRP - 1) / GRP)         // 98
#define BS 64                                    // nodes per bucket
#define BSH 6                                    // log2(BS)
#define NBUCKET ((N_NODES + BS - 1) / BS)        // 782
#define HSZ (NBUCKET * NCHUNK)                   // 305,762
#define PROJ_BLOCKS 1100
#define SORT_CAP 1536      // LDS staging capacity (mean bucket = 1023, sigma ~32)

// offsets into the small fused-weight buffer Wsm (256 floats)
#define OFF_WPP 0
#define OFF_WQQ 49
#define OFF_WR  98
#define OFF_WS  161
#define OFF_BP  224
#define OFF_BQ  231
#define OFF_BR  238
#define OFF_BS  247

// ============ prep: coarse histogram + 4B edge packing + weight packing ============
// packed code: bucket(10) << 22 | dl(6) << 16 | src(16)

__global__ void __launch_bounds__(512) k_prep(
        const int4* __restrict__ edges2,          // 2 edges per int4
        const float* __restrict__ rp_w1, const float* __restrict__ g_w1,
        const float* __restrict__ w3, const float* __restrict__ b3,
        int* __restrict__ histT, uint2* __restrict__ packedE2,
        float* __restrict__ Wbig, float* __restrict__ Wsm) {
    int bid = blockIdx.x, tid = threadIdx.x;
    if (bid < NCHUNK) {
        __shared__ int cnt[NBUCKET];
        for (int i = tid; i < NBUCKET; i += 512) cnt[i] = 0;
        __syncthreads();
        int basePair = bid * (CH / 2);
#pragma unroll
        for (int k = 0; k < CH / 1024; ++k) {
            int pi = basePair + k * 512 + tid;
            if (pi < E_EDGES / 2) {
                int4 e2 = edges2[pi];
                int b0 = e2.y >> BSH, b1 = e2.w >> BSH;
                atomicAdd(&cnt[b0], 1);
                atomicAdd(&cnt[b1], 1);
                uint2 pc;
                pc.x = ((unsigned int)b0 << 22) | ((unsigned int)(e2.y & (BS - 1)) << 16)
                     | (unsigned int)e2.x;
                pc.y = ((unsigned int)b1 << 22) | ((unsigned int)(e2.w & (BS - 1)) << 16)
                     | (unsigned int)e2.z;
                packedE2[pi] = pc;
            }
        }
        __syncthreads();
        for (int i = tid; i < NBUCKET; i += 512) histT[i * NCHUNK + bid] = cnt[i];
        return;
    }
    if (bid < NCHUNK + 8) {   // Wbig: 4096 entries, 8 blocks x 512
        int t = (bid - NCHUNK) * 512 + tid;
        int m = t >> 5, o = t & 31;
        float v;
        if (o < 7)       v = rp_w1[m * 7 + o];
        else if (o < 14) v = rp_w1[(m + 128) * 7 + (o - 7)];
        else if (o < 23) v = g_w1[m * 9 + (o - 14)];
        else             v = g_w1[(m + 128) * 9 + (o - 23)];
        Wbig[m * 32 + o] = v;
        return;
    }
    // Wsm: 256 fused dot-products (threads 0..255)
    int t = tid;
    if (t >= 256) return;
    float acc = 0.f;
    if (t < 49) {
        int i = t / 7, j = t % 7;
        for (int m = 0; m < 128; ++m) acc = fmaf(w3[i * 128 + m], rp_w1[m * 7 + j], acc);
    } else if (t < 98) {
        int u = t - 49; int i = u / 7, j = u % 7;
        for (int m = 0; m < 128; ++m) acc = fmaf(w3[i * 128 + m], rp_w1[(m + 128) * 7 + j], acc);
    } else if (t < 161) {
        int u = t - 98; int i = u / 9, j = u % 9;
        for (int m = 0; m < 128; ++m) acc = fmaf(w3[i * 128 + m], g_w1[m * 9 + j], acc);
    } else if (t < 224) {
        int u = t - 161; int i = u / 9, j = u % 9;
        for (int m = 0; m < 128; ++m) acc = fmaf(w3[i * 128 + m], g_w1[(m + 128) * 9 + j], acc);
    } else if (t < 231) {
        int j = t - 224;
        for (int m = 0; m < 128; ++m) acc = fmaf(b3[m], rp_w1[m * 7 + j], acc);
    } else if (t < 238) {
        int j = t - 231;
        for (int m = 0; m < 128; ++m) acc = fmaf(b3[m], rp_w1[(m + 128) * 7 + j], acc);
    } else if (t < 247) {
        int j = t - 238;
        for (int m = 0; m < 128; ++m) acc = fmaf(b3[m], g_w1[m * 9 + j], acc);
    } else {
        int j = t - 247;
        for (int m = 0; m < 128; ++m) acc = fmaf(b3[m], g_w1[(m + 128) * 9 + j], acc);
    }
    Wsm[t] = acc;
}

// ============ per-bucket exclusive scan over chunks (782 WGs x 512) ============

__global__ void __launch_bounds__(512) k_scanB(const int* __restrict__ histT,
                                               int* __restrict__ histTs,
                                               int* __restrict__ btot) {
    __shared__ int sh[512];
    int b = blockIdx.x, tid = threadIdx.x;
    int v = (tid < NCHUNK) ? histT[b * NCHUNK + tid] : 0;
    sh[tid] = v;
    __syncthreads();
    for (int o = 1; o < 512; o <<= 1) {
        int t2 = (tid >= o) ? sh[tid - o] : 0;
        __syncthreads();
        sh[tid] += t2;
        __syncthreads();
    }
    if (tid < NCHUNK) histTs[b * NCHUNK + tid] = sh[tid] - v;   // local exclusive
    if (tid == 511) btot[b] = sh[511];                           // bucket total
}

// ============ scatter (blocks 0..97, 4 chunks each, in-block base scan)
//              || projection (blocks 98..) ============

__global__ void __launch_bounds__(512) k_scatProj(
        const uint2* __restrict__ packedE2, const int* __restrict__ histTs,
        const int* __restrict__ btot, int* __restrict__ bucketBase,
        unsigned int* __restrict__ bucketed,
        const float* __restrict__ score, const float* __restrict__ Wbig,
        float* __restrict__ p, float* __restrict__ q,
        float* __restrict__ r, float* __restrict__ s) {
    __shared__ int offl[NBUCKET];
    __shared__ int shb[1024];
    const int bid = blockIdx.x, tid = threadIdx.x;
    if (bid < NSCAT) {
        // ---- in-block exclusive scan of btot (every scatter block, redundant) ----
        int v0 = (tid < NBUCKET) ? btot[tid] : 0;
        int v1 = (tid + 512 < NBUCKET) ? btot[tid + 512] : 0;
        shb[tid] = v0;
        shb[tid + 512] = v1;
        __syncthreads();
        for (int o = 1; o < 1024; o <<= 1) {
            int t0 = (tid >= o) ? shb[tid - o] : 0;
            int t1 = (tid + 512 >= o) ? shb[tid + 512 - o] : 0;
            __syncthreads();
            shb[tid] += t0;
            shb[tid + 512] += t1;
            __syncthreads();
        }
        const int c0 = bid * GRP;    // first chunk of this group
        if (tid < NBUCKET) {
            int base = shb[tid] - v0;
            offl[tid] = base + histTs[tid * NCHUNK + c0];
            if (bid == 0) bucketBase[tid] = base;     // publish for k_sortEdge0
        }
        if (tid + 512 < NBUCKET) {
            int base = shb[tid + 512] - v1;
            offl[tid + 512] = base + histTs[(tid + 512) * NCHUNK + c0];
            if (bid == 0) bucketBase[tid + 512] = base;
        }
        if (bid == 0 && tid == 0) bucketBase[NBUCKET] = E_EDGES;
        __syncthreads();
        // ---- scatter 4 chunks (ascending order keeps cursors consistent) ----
        int basePair = bid * (GRP * CH / 2);
#pragma unroll
        for (int k = 0; k < GRP * CH / 1024; ++k) {
            int pi = basePair + k * 512 + tid;
            if (pi < E_EDGES / 2) {
                uint2 c2 = packedE2[pi];
                int pos0 = atomicAdd(&offl[c2.x >> 22], 1);
                bucketed[pos0] = c2.x & 0x3FFFFFu;
                int pos1 = atomicAdd(&offl[c2.y >> 22], 1);
                bucketed[pos1] = c2.y & 0x3FFFFFu;
            }
        }
        return;
    }
    // ---- projection: p,q,r,s = score @ Wbig ----
    int wave = (bid - NSCAT) * 8 + (tid >> 6);
    int lane = tid & 63;
    const int nw = PROJ_BLOCKS * 8;
    int mg = lane >> 3, og = lane & 7;
    const float4* wb4 = reinterpret_cast<const float4*>(Wbig);
    float4 w[16];
#pragma unroll
    for (int i = 0; i < 16; ++i) w[i] = wb4[(mg * 16 + i) * 8 + og];
    for (int n = wave; n < N_NODES; n += nw) {
        const float4* srow = reinterpret_cast<const float4*>(score + n * M_FEAT + mg * 16);
        float a0 = 0.f, a1 = 0.f, a2 = 0.f, a3 = 0.f;
#pragma unroll
        for (int i = 0; i < 4; ++i) {
            float4 sv = srow[i];
            float se[4] = {sv.x, sv.y, sv.z, sv.w};
#pragma unroll
            for (int e = 0; e < 4; ++e) {
                float4 ww = w[i * 4 + e];
                a0 = fmaf(se[e], ww.x, a0);
                a1 = fmaf(se[e], ww.y, a1);
                a2 = fmaf(se[e], ww.z, a2);
                a3 = fmaf(se[e], ww.w, a3);
            }
        }
#pragma unroll
        for (int off = 32; off >= 8; off >>= 1) {
            a0 += __shfl_down(a0, off);
            a1 += __shfl_down(a1, off);
            a2 += __shfl_down(a2, off);
            a3 += __shfl_down(a3, off);
        }
        if (mg == 0) {
            float outv[4] = {a0, a1, a2, a3};
#pragma unroll
            for (int jj = 0; jj < 4; ++jj) {
                int o = og * 4 + jj;
                float v = outv[jj];
                if (o < 7)       p[n * PRP + o] = v;
                else if (o < 14) q[n * PRP + (o - 7)] = v;
                else if (o < 23) r[n * PG + (o - 14)] = v;
                else             s[n * PG + (o - 23)] = v;
            }
        }
    }
}

// ============ fused: per-bucket fine sort (LDS-staged) + round-0 edge pass ============

__global__ void __launch_bounds__(512) k_sortEdge0(
        const unsigned int* __restrict__ bucketed, const int* __restrict__ bucketBase,
        unsigned short* __restrict__ srcSorted16, int* __restrict__ off,
        const float* __restrict__ pIn, float* __restrict__ pOut,
        float* __restrict__ q, float* __restrict__ Hs,
        const float* __restrict__ w2, const float* __restrict__ b1,
        const float* __restrict__ b2, const float* __restrict__ Wsm) {
    __shared__ int cnt[BS], loc[BS], cur[BS], shs[BS];
    __shared__ unsigned short srcL[SORT_CAP];
    const int bid = blockIdx.x, tid = threadIdx.x;
    const int d0 = bid << BSH;

    if (tid < BS) { cnt[tid] = 0; cur[tid] = 0; }
    __syncthreads();
    const int base0 = bucketBase[bid];
    const int base1 = bucketBase[bid + 1];
    const int nb = base1 - base0;

    for (int i = base0 + tid; i < base1; i += 512)
        atomicAdd(&cnt[bucketed[i] >> 16], 1);
    __syncthreads();
    int v = (tid < BS) ? cnt[tid] : 0;
    if (tid < BS) shs[tid] = v;
    __syncthreads();
    for (int o = 1; o < BS; o <<= 1) {
        int t2 = (tid < BS && tid >= o) ? shs[tid - o] : 0;
        __syncthreads();
        if (tid < BS) shs[tid] += t2;
        __syncthreads();
    }
    if (tid < BS) {
        loc[tid] = shs[tid] - v;    // bucket-local exclusive prefix
        int n = d0 + tid;
        if (n < N_NODES) off[n] = base0 + loc[tid];
    }
    if (bid == 0 && tid == 0) off[N_NODES] = E_EDGES;
    __syncthreads();

    const bool inLds = (nb <= SORT_CAP);
    for (int i = base0 + tid; i < base1; i += 512) {
        unsigned int ec = bucketed[i];
        int dl = (int)(ec >> 16);
        int pos = loc[dl] + atomicAdd(&cur[dl], 1);
        unsigned short sv = (unsigned short)(ec & 0xFFFF);
        srcSorted16[base0 + pos] = sv;
        if (inLds) srcL[pos] = sv;
    }
    __syncthreads();

    // ---- round-0 edge MLP: 8 lanes per node, from LDS ----
    int li = tid >> 3, sub = tid & 7;
    int n = d0 + li;
    if (n >= N_NODES) return;
    float w2r[49], qr[7], b2r[7], acc[7];
#pragma unroll
    for (int i = 0; i < 49; ++i) w2r[i] = w2[i];
    {
        float4 qa = *reinterpret_cast<const float4*>(q + n * PRP);
        float4 qb4 = *reinterpret_cast<const float4*>(q + n * PRP + 4);
        qr[0] = qa.x + b1[0]; qr[1] = qa.y + b1[1]; qr[2] = qa.z + b1[2];
        qr[3] = qa.w + b1[3]; qr[4] = qb4.x + b1[4]; qr[5] = qb4.y + b1[5];
        qr[6] = qb4.z + b1[6];
    }
#pragma unroll
    for (int k = 0; k < 7; ++k) { b2r[k] = b2[k]; acc[k] = 0.f; }
    int l0 = loc[li], dg = cnt[li];
    for (int pos = l0 + sub; pos < l0 + dg; pos += 8) {
        int src = inLds ? (int)srcL[pos] : (int)srcSorted16[base0 + pos];
        float4 pa = *reinterpret_cast<const float4*>(pIn + src * PRP);
        float4 pb = *reinterpret_cast<const float4*>(pIn + src * PRP + 4);
        float h1[7];
        h1[0] = fmaxf(pa.x + qr[0], 0.f);
        h1[1] = fmaxf(pa.y + qr[1], 0.f);
        h1[2] = fmaxf(pa.z + qr[2], 0.f);
        h1[3] = fmaxf(pa.w + qr[3], 0.f);
        h1[4] = fmaxf(pb.x + qr[4], 0.f);
        h1[5] = fmaxf(pb.y + qr[5], 0.f);
        h1[6] = fmaxf(pb.z + qr[6], 0.f);
#pragma unroll
        for (int j = 0; j < 7; ++j) {
            float vv = b2r[j];
#pragma unroll
            for (int k = 0; k < 7; ++k) vv = fmaf(h1[k], w2r[k * 7 + j], vv);
            acc[j] += fmaxf(vv, 0.f);
        }
    }
#pragma unroll
    for (int j = 0; j < 7; ++j) {
        acc[j] += __shfl_down(acc[j], 4);
        acc[j] += __shfl_down(acc[j], 2);
        acc[j] += __shfl_down(acc[j], 1);
    }
    int baseLane = (threadIdx.x & 63) & ~7;
    float hb[7];
#pragma unroll
    for (int j = 0; j < 7; ++j) hb[j] = __shfl(acc[j], baseLane);
    if (sub < 7) {
        int j = sub;
        Hs[n * PRP + j] = hb[j];
        float degf = (float)dg;
        float vp = degf * Wsm[OFF_BP + j];
        float vq = degf * Wsm[OFF_BQ + j];
#pragma unroll
        for (int i2 = 0; i2 < 7; ++i2) {
            vp = fmaf(hb[i2], Wsm[OFF_WPP + i2 * 7 + j], vp);
            vq = fmaf(hb[i2], Wsm[OFF_WQQ + i2 * 7 + j], vq);
        }
        pOut[n * PRP + j] = pIn[n * PRP + j] + vp;
        q[n * PRP + j] += vq;
    }
}

// ============ edge rounds 1,2: CSR (uint16), 8 lanes/node, no atomics ============

template <int ROUND>
__global__ void __launch_bounds__(512) k_edgeC(
        const unsigned short* __restrict__ srcSorted16, const int* __restrict__ off,
        const float* __restrict__ pIn, float* __restrict__ pOut,
        float* __restrict__ q, float* __restrict__ Hs,
        const float* __restrict__ w2, const float* __restrict__ b1,
        const float* __restrict__ b2, const float* __restrict__ Wsm) {
    int gt = blockIdx.x * 512 + threadIdx.x;
    int n = gt >> 3, sub = gt & 7;
    if (n >= N_NODES) return;
    float w2r[49], qr[7], b2r[7], acc[7];
#pragma unroll
    for (int i = 0; i < 49; ++i) w2r[i] = w2[i];
    {
        float4 qa = *reinterpret_cast<const float4*>(q + n * PRP);
        float4 qb4 = *reinterpret_cast<const float4*>(q + n * PRP + 4);
        qr[0] = qa.x + b1[0]; qr[1] = qa.y + b1[1]; qr[2] = qa.z + b1[2];
        qr[3] = qa.w + b1[3]; qr[4] = qb4.x + b1[4]; qr[5] = qb4.y + b1[5];
        qr[6] = qb4.z + b1[6];
    }
#pragma unroll
    for (int k = 0; k < 7; ++k) { b2r[k] = b2[k]; acc[k] = 0.f; }
    int s0 = off[n], s1 = off[n + 1];
    for (int pos = s0 + sub; pos < s1; pos += 8) {
        int src = (int)srcSorted16[pos];
        float4 pa = *reinterpret_cast<const float4*>(pIn + src * PRP);
        float4 pb = *reinterpret_cast<const float4*>(pIn + src * PRP + 4);
        float h1[7];
        h1[0] = fmaxf(pa.x + qr[0], 0.f);
        h1[1] = fmaxf(pa.y + qr[1], 0.f);
        h1[2] = fmaxf(pa.z + qr[2], 0.f);
        h1[3] = fmaxf(pa.w + qr[3], 0.f);
        h1[4] = fmaxf(pb.x + qr[4], 0.f);
        h1[5] = fmaxf(pb.y + qr[5], 0.f);
        h1[6] = fmaxf(pb.z + qr[6], 0.f);
#pragma unroll
        for (int j = 0; j < 7; ++j) {
            float vv = b2r[j];
#pragma unroll
            for (int k = 0; k < 7; ++k) vv = fmaf(h1[k], w2r[k * 7 + j], vv);
            acc[j] += fmaxf(vv, 0.f);
        }
    }
#pragma unroll
    for (int j = 0; j < 7; ++j) {
        acc[j] += __shfl_down(acc[j], 4);
        acc[j] += __shfl_down(acc[j], 2);
        acc[j] += __shfl_down(acc[j], 1);
    }
    int baseLane = (threadIdx.x & 63) & ~7;
    float hb[7];
#pragma unroll
    for (int j = 0; j < 7; ++j) hb[j] = __shfl(acc[j], baseLane);
    if (sub < 7) {
        int j = sub;
        Hs[n * PRP + j] += hb[j];
        if (ROUND < 2) {
            float degf = (float)(s1 - s0);
            float vp = degf * Wsm[OFF_BP + j];
            float vq = degf * Wsm[OFF_BQ + j];
#pragma unroll
            for (int i2 = 0; i2 < 7; ++i2) {
                vp = fmaf(hb[i2], Wsm[OFF_WPP + i2 * 7 + j], vp);
                vq = fmaf(hb[i2], Wsm[OFF_WQQ + i2 * 7 + j], vq);
            }
            pOut[n * PRP + j] = pIn[n * PRP + j] + vp;
            q[n * PRP + j] += vq;
        }
    }
}

// ============ pair scorer with fused r/s finalization (deg from CSR) ============

__global__ void k_pair(const int2* __restrict__ lab2, const float* __restrict__ r,
                       const float* __restrict__ s, const float* __restrict__ Hs,
                       const int* __restrict__ off, const float* __restrict__ Wsm,
                       const float* __restrict__ w2, const float* __restrict__ b1,
                       const float* __restrict__ b2, const float* __restrict__ w3,
                       const float* __restrict__ b3, float* __restrict__ out) {
    int b = blockIdx.x * blockDim.x + threadIdx.x;
    if (b >= B_PAIRS) return;
    int2 ab = lab2[b];
    int a0 = ab.x, a1 = ab.y;
    float h0[7], h1v[7];
#pragma unroll
    for (int k = 0; k < 7; ++k) { h0[k] = Hs[a0 * PRP + k]; h1v[k] = Hs[a1 * PRP + k]; }
    float d30 = 3.f * (float)(off[a0 + 1] - off[a0]);
    float d31 = 3.f * (float)(off[a1 + 1] - off[a1]);
    float g1[9];
#pragma unroll
    for (int j = 0; j < 9; ++j) {
        float vr = r[a0 * PG + j] + d30 * Wsm[OFF_BR + j];
        float vs = s[a1 * PG + j] + d31 * Wsm[OFF_BS + j];
#pragma unroll
        for (int i = 0; i < 7; ++i) {
            vr = fmaf(h0[i], Wsm[OFF_WR + i * 9 + j], vr);
            vs = fmaf(h1v[i], Wsm[OFF_WS + i * 9 + j], vs);
        }
        g1[j] = fmaxf(vr + vs + b1[j], 0.f);
    }
    float logit = b3[0];
#pragma unroll
    for (int j = 0; j < 9; ++j) {
        float v = b2[j];
#pragma unroll
        for (int k = 0; k < 9; ++k) v = fmaf(g1[k], w2[k * 9 + j], v);
        logit = fmaf(fmaxf(v, 0.f), w3[j], logit);
    }
    out[b] = 1.f / (1.f + expf(-logit));
}

// ---------------- launch: 7 dispatches ----------------

extern "C" void kernel_launch(void* const* d_in, const int* in_sizes, int n_in,
                              void* d_out, int out_size, void* d_ws, size_t ws_size,
                              hipStream_t stream) {
    const float* score = (const float*)d_in[0];
    const int4*  edges2 = (const int4*)d_in[1];
    const int2*  lab2  = (const int2*)d_in[2];
    const float* rp_w1 = (const float*)d_in[3];
    const float* rp_b1 = (const float*)d_in[4];
    const float* rp_w2 = (const float*)d_in[5];
    const float* rp_b2 = (const float*)d_in[6];
    const float* rp_w3 = (const float*)d_in[7];
    const float* rp_b3 = (const float*)d_in[8];
    const float* g_w1  = (const float*)d_in[9];
    const float* g_b1  = (const float*)d_in[10];
    const float* g_w2  = (const float*)d_in[11];
    const float* g_b2  = (const float*)d_in[12];
    const float* g_w3  = (const float*)d_in[13];
    const float* g_b3  = (const float*)d_in[14];
    float* out = (float*)d_out;

    float* ws   = (float*)d_ws;
    float* pA   = ws;                      // N*8
    float* pB   = pA + N_NODES * PRP;      // N*8
    float* q    = pB + N_NODES * PRP;      // N*8
    float* Hs   = q + N_NODES * PRP;       // N*8
    float* r    = Hs + N_NODES * PRP;      // N*16
    float* s    = r + N_NODES * PG;        // N*16
    float* Wbig = s + N_NODES * PG;        // 4096
    float* Wsm  = Wbig + 4096;             // 256
    unsigned int* packedE  = (unsigned int*)(Wsm + 256);   // E (uint2-aligned)
    unsigned int* bucketed = packedE + E_EDGES;            // E
    unsigned short* srcSorted16 = (unsigned short*)(bucketed + E_EDGES);  // E uint16
    int* histT      = (int*)(srcSorted16 + E_EDGES);       // HSZ
    int* histTs     = histT + HSZ;                         // HSZ
    int* btot       = histTs + HSZ;                        // NBUCKET
    int* bucketBase = btot + NBUCKET;                      // NBUCKET+1
    int* off        = bucketBase + NBUCKET + 1;            // N+1

    k_prep<<<NCHUNK + 9, 512, 0, stream>>>(edges2, rp_w1, g_w1, rp_w3, rp_b3,
                                           histT, (uint2*)packedE, Wbig, Wsm);
    k_scanB<<<NBUCKET, 512, 0, stream>>>(histT, histTs, btot);
    k_scatProj<<<NSCAT + PROJ_BLOCKS, 512, 0, stream>>>((const uint2*)packedE, histTs,
                                                        btot, bucketBase, bucketed,
                                                        score, Wbig, pA, q, r, s);
    k_sortEdge0<<<NBUCKET, 512, 0, stream>>>(bucketed, bucketBase, srcSorted16, off,
                                             pA, pB, q, Hs, rp_w2, rp_b1, rp_b2, Wsm);
    k_edgeC<1><<<(8 * N_NODES + 511) / 512, 512, 0, stream>>>(srcSorted16, off, pB, pA, q, Hs,
                                                              rp_w2, rp_b1, rp_b2, Wsm);
    k_edgeC<2><<<(8 * N_NODES + 511) / 512, 512, 0, stream>>>(srcSorted16, off, pA, pB, q, Hs,
                                                              rp_w2, rp_b1, rp_b2, Wsm);
    k_pair<<<(B_PAIRS + 255) / 256, 256, 0, stream>>>(lab2, r, s, Hs, off, Wsm,
                                                      g_w2, g_b1, g_b2, g_w3, g_b3, out);
}